// Round 10
// baseline (188.919 us; speedup 1.0000x reference)
//
#include <hip/hip_runtime.h>

#define DIMSZ 2048
#define NH 32
#define NKV 8
#define HD 64
#define SEQLEN 2048
#define BATCH 2
#define NROWS (BATCH*SEQLEN)   // 4096
#define NQKVC 3072             // 2048 q + 512 k + 512 v

typedef __bf16 bf16x8 __attribute__((ext_vector_type(8)));
typedef __bf16 bf16x2 __attribute__((ext_vector_type(2)));
typedef float f32x4v __attribute__((ext_vector_type(4)));
typedef float f32x2v __attribute__((ext_vector_type(2)));
typedef float f32x16 __attribute__((ext_vector_type(16)));

__device__ __forceinline__ unsigned short f2bf(float f) {
  __bf16 h = (__bf16)f;
  union { __bf16 h; unsigned short u; } v; v.h = h; return v.u;
}
__device__ __forceinline__ unsigned int pk2bf(float lo, float hi) {
  f32x2v v; v[0] = lo; v[1] = hi;
  bf16x2 h = __builtin_convertvector(v, bf16x2);
  union { bf16x2 h; unsigned int u; } c; c.h = h; return c.u;
}
// XOR swizzle for LDS tiles with 128-byte rows.
__device__ __forceinline__ int swz128(int row, int colBytes) {
  return row * 128 + (colBytes ^ ((row & 7) << 4));
}

#define GLOAD16(g, l) __builtin_amdgcn_global_load_lds( \
    (const __attribute__((address_space(1))) unsigned int*)(g), \
    (__attribute__((address_space(3))) unsigned int*)(l), 16, 0, 0)

// ---------------- merged fp32 -> bf16 convert (x | wq|wk|wv | wo) ----------------
__global__ void k_cvt_all(const float* __restrict__ x,
                          const float* __restrict__ wq, const float* __restrict__ wk,
                          const float* __restrict__ wv, const float* __restrict__ wo,
                          unsigned short* __restrict__ xb,
                          unsigned short* __restrict__ wqkvb,
                          unsigned short* __restrict__ wob) {
  int i = blockIdx.x * 256 + threadIdx.x;   // 4,718,592 float4 total
  const float* s; unsigned short* d; int soff, doff;
  if (i < 2097152)        { s = x;  d = xb;    soff = i;           doff = i; }
  else if (i < 3145728)   { s = wq; d = wqkvb; soff = i - 2097152; doff = i - 2097152; }
  else if (i < 3407872)   { s = wk; d = wqkvb; soff = i - 3145728; doff = i - 2097152; }
  else if (i < 3670016)   { s = wv; d = wqkvb; soff = i - 3407872; doff = i - 2097152; }
  else                    { s = wo; d = wob;   soff = i - 3670016; doff = i - 3670016; }
  float4 v = reinterpret_cast<const float4*>(s)[soff];
  uint2 pk; pk.x = pk2bf(v.x, v.y); pk.y = pk2bf(v.z, v.w);
  reinterpret_cast<uint2*>(d)[doff] = pk;
}

// ---------------- QKV GEMM with fused RoPE / V-transpose epilogue ----------------
__global__ __launch_bounds__(256, 2) void k_gemm_qkv(
    const unsigned short* __restrict__ A,
    const unsigned short* __restrict__ B,
    const float* __restrict__ fc, const float* __restrict__ fs,
    unsigned short* __restrict__ Qb, unsigned short* __restrict__ Kb,
    unsigned short* __restrict__ Vt)
{
  constexpr int BK = 64, K = DIMSZ;
  __shared__ __attribute__((aligned(16))) unsigned short smA[128 * BK];
  __shared__ __attribute__((aligned(16))) unsigned short smB[128 * BK];
  const int tid = threadIdx.x;
  const int lane = tid & 63;
  const int wid = tid >> 6;
  const int lr = lane & 15, lg = lane >> 4;
  const int gx = gridDim.x;
  int lin = blockIdx.y * gx + blockIdx.x;
  const int cpx = (gx * gridDim.y) >> 3;
  lin = (lin & 7) * cpx + (lin >> 3);
  const int m0 = (lin / gx) * 128, n0 = (lin % gx) * 128;
  const int wr = (wid >> 1) * 64, wc = (wid & 1) * 64;

  f32x4v acc[4][4];
  #pragma unroll
  for (int i = 0; i < 4; i++)
    #pragma unroll
    for (int j = 0; j < 4; j++)
      acc[i][j] = f32x4v{0.f, 0.f, 0.f, 0.f};

  for (int k0 = 0; k0 < K; k0 += BK) {
    #pragma unroll
    for (int c = 0; c < 4; c++) {
      const int chunk = wid * 4 + c;
      const int idx = chunk * 64 + lane;
      const int row = idx >> 3, s = idx & 7;
      const int ks = (s ^ (row & 7)) * 8;
      GLOAD16(A + (size_t)(m0 + row) * K + k0 + ks, &smA[chunk * 512]);
      GLOAD16(B + (size_t)(n0 + row) * K + k0 + ks, &smB[chunk * 512]);
    }
    __syncthreads();
    #pragma unroll
    for (int ks = 0; ks < 2; ks++) {
      bf16x8 af[4], bfv[4];
      #pragma unroll
      for (int m = 0; m < 4; m++)
        af[m] = *reinterpret_cast<const bf16x8*>((char*)smA + swz128(wr + m * 16 + lr, ks * 64 + lg * 16));
      #pragma unroll
      for (int n = 0; n < 4; n++)
        bfv[n] = *reinterpret_cast<const bf16x8*>((char*)smB + swz128(wc + n * 16 + lr, ks * 64 + lg * 16));
      #pragma unroll
      for (int m = 0; m < 4; m++)
        #pragma unroll
        for (int n = 0; n < 4; n++)
          acc[m][n] = __builtin_amdgcn_mfma_f32_16x16x32_bf16(af[m], bfv[n], acc[m][n], 0, 0, 0);
    }
    __syncthreads();
  }
  const int bx = n0 >> 7;
  if (bx < 20) {
    const bool isQ = bx < 16;
    const float SCL = isQ ? 0.18033688011112043f : 1.0f;   // 0.125*log2(e) for Q
    #pragma unroll
    for (int n = 0; n < 4; n++) {
      const int col = n0 + wc + n * 16 + lr;
      const int d = col & 63;
      const int i = d >> 1;
      const float sgn = (d & 1) ? 1.0f : -1.0f;
      unsigned short* dst;
      if (isQ) dst = Qb + (size_t)(col >> 6) * (SEQLEN * HD) + d;
      else     dst = Kb + (size_t)((col - 2048) >> 6) * (SEQLEN * HD) + d;
      #pragma unroll
      for (int m = 0; m < 4; m++)
        #pragma unroll
        for (int r = 0; r < 4; r++) {
          const int row = m0 + wr + m * 16 + lg * 4 + r;
          const int s = row & (SEQLEN - 1), b = row >> 11;
          const float v = acc[m][n][r];
          const float p = __shfl_xor(v, 1);
          const float c = fc[s * 32 + i], sn = fs[s * 32 + i];
          const float o = (v * c + sgn * p * sn) * SCL;
          const size_t headStride = (size_t)(isQ ? NH : NKV) * SEQLEN * HD;
          dst[(size_t)b * headStride + (size_t)s * HD] = f2bf(o);
        }
    }
  } else {
    #pragma unroll
    for (int n = 0; n < 4; n++) {
      const int col = n0 + wc + n * 16 + lr;
      const int kvh = (col - 2560) >> 6, d = col & 63;
      #pragma unroll
      for (int m = 0; m < 4; m++) {
        const int row0 = m0 + wr + m * 16 + lg * 4;
        const int s0 = row0 & (SEQLEN - 1), b = row0 >> 11;
        uint2 pk;
        pk.x = pk2bf(acc[m][n][0], acc[m][n][1]);
        pk.y = pk2bf(acc[m][n][2], acc[m][n][3]);
        *reinterpret_cast<uint2*>(
            Vt + ((size_t)((b * NKV + kvh) * HD) + d) * SEQLEN + s0) = pk;
      }
    }
  }
}

// ---------------- GEMM: C[M][N] = A[M][K] * B[N][K]^T (O-projection) ----------------
template<int OUT_BF16>
__global__ __launch_bounds__(256, 2) void k_gemm_bt(
    const unsigned short* __restrict__ A,
    const unsigned short* __restrict__ B,
    void* __restrict__ Cv, int M, int N, int K)
{
  constexpr int BK = 64;
  __shared__ __attribute__((aligned(16))) unsigned short smA[128 * BK];
  __shared__ __attribute__((aligned(16))) unsigned short smB[128 * BK];
  const int tid = threadIdx.x;
  const int lane = tid & 63;
  const int wid = tid >> 6;
  const int lr = lane & 15, lg = lane >> 4;
  const int gx = gridDim.x;
  int lin = blockIdx.y * gx + blockIdx.x;
  const int cpx = (gx * gridDim.y) >> 3;
  lin = (lin & 7) * cpx + (lin >> 3);
  const int m0 = (lin / gx) * 128, n0 = (lin % gx) * 128;
  const int wr = (wid >> 1) * 64, wc = (wid & 1) * 64;

  f32x4v acc[4][4];
  #pragma unroll
  for (int i = 0; i < 4; i++)
    #pragma unroll
    for (int j = 0; j < 4; j++)
      acc[i][j] = f32x4v{0.f, 0.f, 0.f, 0.f};

  for (int k0 = 0; k0 < K; k0 += BK) {
    #pragma unroll
    for (int c = 0; c < 4; c++) {
      const int chunk = wid * 4 + c;
      const int idx = chunk * 64 + lane;
      const int row = idx >> 3, s = idx & 7;
      const int ks = (s ^ (row & 7)) * 8;
      GLOAD16(A + (size_t)(m0 + row) * K + k0 + ks, &smA[chunk * 512]);
      GLOAD16(B + (size_t)(n0 + row) * K + k0 + ks, &smB[chunk * 512]);
    }
    __syncthreads();
    #pragma unroll
    for (int ks = 0; ks < 2; ks++) {
      bf16x8 af[4], bfv[4];
      #pragma unroll
      for (int m = 0; m < 4; m++)
        af[m] = *reinterpret_cast<const bf16x8*>((char*)smA + swz128(wr + m * 16 + lr, ks * 64 + lg * 16));
      #pragma unroll
      for (int n = 0; n < 4; n++)
        bfv[n] = *reinterpret_cast<const bf16x8*>((char*)smB + swz128(wc + n * 16 + lr, ks * 64 + lg * 16));
      #pragma unroll
      for (int m = 0; m < 4; m++)
        #pragma unroll
        for (int n = 0; n < 4; n++)
          acc[m][n] = __builtin_amdgcn_mfma_f32_16x16x32_bf16(af[m], bfv[n], acc[m][n], 0, 0, 0);
    }
    __syncthreads();
  }
  #pragma unroll
  for (int m = 0; m < 4; m++)
    #pragma unroll
    for (int n = 0; n < 4; n++)
      #pragma unroll
      for (int r = 0; r < 4; r++) {
        const size_t row = m0 + wr + m * 16 + lg * 4 + r;
        const size_t col = n0 + wc + n * 16 + lr;
        if (OUT_BF16) ((unsigned short*)Cv)[row * N + col] = f2bf(acc[m][n][r]);
        else          ((float*)Cv)[row * N + col] = acc[m][n][r];
      }
}

// ---------------- flash attention: 32x32 MFMA, 4 waves x 32 q-rows ----------------
// Round 10: keep round-9's 1024-block balanced grid, but __launch_bounds__(256,2)
// — round 9's (256,4) capped VGPR at 64 and spilled acc/S to scratch (4x HBM
// traffic). At ~104 VGPR (<=128) the HW can still co-schedule 4 blocks/CU.
__global__ __launch_bounds__(256, 2) void k_attn(
    const unsigned short* __restrict__ Qg,   // [B][NH][S][HD], scaled 0.125*log2e
    const unsigned short* __restrict__ Kg,   // [B][NKV][S][HD]
    const unsigned short* __restrict__ Vt,   // [B][NKV][HD][S]
    unsigned short* __restrict__ Og)         // [B*S][NH*HD]
{
  constexpr int KVB = 64;
  __shared__ __attribute__((aligned(16))) unsigned short sK0[KVB * HD];
  __shared__ __attribute__((aligned(16))) unsigned short sK1[KVB * HD];
  __shared__ __attribute__((aligned(16))) unsigned short sV0[HD * KVB];
  __shared__ __attribute__((aligned(16))) unsigned short sV1[HD * KVB];
  const int tid = threadIdx.x;
  const int lane = tid & 63, wid = tid >> 6;       // 4 waves
  const int l31 = lane & 31, hi = lane >> 5;
  // balanced mapping: g -> (panel, head-in-group, qt)
  const int g = blockIdx.x;                        // 1024 blocks
  const int i = g >> 3;                            // 128 per XCD (g&7 = XCD)
  const int r = i >> 5;                            // round 0..3
  const int c = i & 31;
  const int p = (g & 7) * 2 + (c >> 4);            // panel 0..15
  const int kvh = p & 7, b = p >> 3;
  const int h = kvh * 4 + r;
  const int s4 = c & 15;
  const int qt = (r & 1) ? s4 : 15 - s4;           // per-CU sum of qt ~ const
  const unsigned short* Qp = Qg + ((size_t)(b * NH + h) * SEQLEN) * HD;
  const unsigned short* Kp = Kg + ((size_t)(b * NKV + kvh) * SEQLEN) * HD;
  const unsigned short* Vp = Vt + ((size_t)(b * NKV + kvh) * HD) * SEQLEN;

  // staging: 8 chunks of 1KB per 8KB tile; wave wid owns chunks 2wid, 2wid+1
  int srow[2], scol[2];
  #pragma unroll
  for (int cc = 0; cc < 2; cc++) {
    const int idx = (wid * 2 + cc) * 64 + lane;
    srow[cc] = idx >> 3;
    scol[cc] = ((idx & 7) ^ (srow[cc] & 7)) * 8;
  }

  const int qrow0 = qt * 128 + wid * 32;
  const int qg = qrow0 + l31;                      // this lane's q-row
  bf16x8 aq[4];                                    // Q B-frags: k-slice ks*16+hi*8
  #pragma unroll
  for (int ks = 0; ks < 4; ks++)
    aq[ks] = *reinterpret_cast<const bf16x8*>(Qp + (size_t)qg * HD + ks * 16 + hi * 8);

  f32x16 accO0, accO1;
  #pragma unroll
  for (int ii = 0; ii < 16; ii++) { accO0[ii] = 0.f; accO1[ii] = 0.f; }
  float mrun = -3.0e38f, lrun = 0.f;               // log2-domain state for q=qg

  auto compute = [&](int kv0, auto& sKb, auto& sVb) {
    if (kv0 > qrow0 + 31) return;
    f32x16 S0, S1;
    #pragma unroll
    for (int ii = 0; ii < 16; ii++) { S0[ii] = 0.f; S1[ii] = 0.f; }
    __builtin_amdgcn_s_setprio(1);
    #pragma unroll
    for (int ks = 0; ks < 4; ks++) {
      bf16x8 ak0 = *reinterpret_cast<const bf16x8*>((char*)sKb + swz128(l31,      ks * 32 + hi * 16));
      bf16x8 ak1 = *reinterpret_cast<const bf16x8*>((char*)sKb + swz128(32 + l31, ks * 32 + hi * 16));
      S0 = __builtin_amdgcn_mfma_f32_32x32x16_bf16(ak0, aq[ks], S0, 0, 0, 0);
      S1 = __builtin_amdgcn_mfma_f32_32x32x16_bf16(ak1, aq[ks], S1, 0, 0, 0);
    }
    __builtin_amdgcn_s_setprio(0);
    if (kv0 + KVB - 1 > qrow0) {                   // boundary tile: causal mask
      #pragma unroll
      for (int reg = 0; reg < 16; reg++) {
        const int rl = (reg & 3) + 8 * (reg >> 2) + (hi << 2);
        if (kv0 + rl > qg)      S0[reg] = -1.0e30f;
        if (kv0 + 32 + rl > qg) S1[reg] = -1.0e30f;
      }
    }
    // row max: pairwise tree (depth 5) + 1 cross-half exchange
    float t16[16];
    #pragma unroll
    for (int ii = 0; ii < 16; ii++) t16[ii] = fmaxf(S0[ii], S1[ii]);
    float t8[8];
    #pragma unroll
    for (int ii = 0; ii < 8; ii++) t8[ii] = fmaxf(t16[ii], t16[ii + 8]);
    float t4[4];
    #pragma unroll
    for (int ii = 0; ii < 4; ii++) t4[ii] = fmaxf(t8[ii], t8[ii + 4]);
    float tm = fmaxf(fmaxf(t4[0], t4[1]), fmaxf(t4[2], t4[3]));
    tm = fmaxf(tm, __shfl_xor(tm, 32));
    const float mo = mrun;
    const bool defer = __all(tm <= mo + 8.0f);     // T13, log2 domain
    const float mn = defer ? mo : fmaxf(mo, tm);
    #pragma unroll
    for (int ii = 0; ii < 16; ii++) {
      S0[ii] = __builtin_amdgcn_exp2f(S0[ii] - mn);
      S1[ii] = __builtin_amdgcn_exp2f(S1[ii] - mn);
    }
    // row sum: pairwise tree
    float u16[16];
    #pragma unroll
    for (int ii = 0; ii < 16; ii++) u16[ii] = S0[ii] + S1[ii];
    float u8[8];
    #pragma unroll
    for (int ii = 0; ii < 8; ii++) u8[ii] = u16[ii] + u16[ii + 8];
    float u4[4];
    #pragma unroll
    for (int ii = 0; ii < 4; ii++) u4[ii] = u8[ii] + u8[ii + 4];
    float rs = (u4[0] + u4[1]) + (u4[2] + u4[3]);
    rs += __shfl_xor(rs, 32);
    if (defer) {
      lrun += rs;
    } else {
      const float sc = __builtin_amdgcn_exp2f(mo - mn);
      mrun = mn;
      lrun = lrun * sc + rs;
      #pragma unroll
      for (int reg = 0; reg < 16; reg++) {
        const int rl = (reg & 3) + 8 * (reg >> 2) + (hi << 2);
        const float scr = __shfl(sc, rl);
        accO0[reg] *= scr; accO1[reg] *= scr;
      }
    }
    // PV: build A-frags in-register (T12) and accumulate O[q][d]
    __builtin_amdgcn_s_setprio(1);
    #define PVSTEP(S16, G, CB) do {                                          \
      unsigned a0 = pk2bf(S16[(G)+0], S16[(G)+1]);                           \
      unsigned a1 = pk2bf(S16[(G)+2], S16[(G)+3]);                           \
      unsigned b0 = pk2bf(S16[(G)+4], S16[(G)+5]);                           \
      unsigned b1 = pk2bf(S16[(G)+6], S16[(G)+7]);                           \
      unsigned s0 = hi ? a0 : b0, s1 = hi ? a1 : b1;                         \
      unsigned r0 = __shfl_xor((int)s0, 32), r1 = __shfl_xor((int)s1, 32);   \
      union { unsigned u[4]; bf16x8 v; } pf;                                 \
      pf.u[0] = hi ? r0 : a0; pf.u[1] = hi ? r1 : a1;                        \
      pf.u[2] = hi ? b0 : r0; pf.u[3] = hi ? b1 : r1;                        \
      bf16x8 bv0 = *reinterpret_cast<const bf16x8*>((char*)sVb + swz128(l31,      (CB))); \
      bf16x8 bv1 = *reinterpret_cast<const bf16x8*>((char*)sVb + swz128(32 + l31, (CB))); \
      accO0 = __builtin_amdgcn_mfma_f32_32x32x16_bf16(pf.v, bv0, accO0, 0, 0, 0); \
      accO1 = __builtin_amdgcn_mfma_f32_32x32x16_bf16(pf.v, bv1, accO1, 0, 0, 0); \
    } while (0)
    PVSTEP(S0, 0,  0  + hi * 16);
    PVSTEP(S0, 8,  32 + hi * 16);
    PVSTEP(S1, 0,  64 + hi * 16);
    PVSTEP(S1, 8,  96 + hi * 16);
    #undef PVSTEP
    __builtin_amdgcn_s_setprio(0);
  };

  const int nt = qt * 2 + 2;    // always even
  GLOAD16(Kp + (size_t)srow[0] * HD + scol[0], &sK0[(wid * 2 + 0) * 512]);
  GLOAD16(Kp + (size_t)srow[1] * HD + scol[1], &sK0[(wid * 2 + 1) * 512]);
  GLOAD16(Vp + (size_t)srow[0] * SEQLEN + scol[0], &sV0[(wid * 2 + 0) * 512]);
  GLOAD16(Vp + (size_t)srow[1] * SEQLEN + scol[1], &sV0[(wid * 2 + 1) * 512]);
  __syncthreads();
  for (int t = 0; t < nt; t += 2) {
    {
      const int kn = (t + 1) * KVB;
      GLOAD16(Kp + (size_t)(kn + srow[0]) * HD + scol[0], &sK1[(wid * 2 + 0) * 512]);
      GLOAD16(Kp + (size_t)(kn + srow[1]) * HD + scol[1], &sK1[(wid * 2 + 1) * 512]);
      GLOAD16(Vp + (size_t)srow[0] * SEQLEN + kn + scol[0], &sV1[(wid * 2 + 0) * 512]);
      GLOAD16(Vp + (size_t)srow[1] * SEQLEN + kn + scol[1], &sV1[(wid * 2 + 1) * 512]);
    }
    compute(t * KVB, sK0, sV0);
    __syncthreads();
    if (t + 2 < nt) {
      const int kn = (t + 2) * KVB;
      GLOAD16(Kp + (size_t)(kn + srow[0]) * HD + scol[0], &sK0[(wid * 2 + 0) * 512]);
      GLOAD16(Kp + (size_t)(kn + srow[1]) * HD + scol[1], &sK0[(wid * 2 + 1) * 512]);
      GLOAD16(Vp + (size_t)srow[0] * SEQLEN + kn + scol[0], &sV0[(wid * 2 + 0) * 512]);
      GLOAD16(Vp + (size_t)srow[1] * SEQLEN + kn + scol[1], &sV0[(wid * 2 + 1) * 512]);
    }
    compute((t + 1) * KVB, sK1, sV1);
    __syncthreads();
  }
  // normalize + store: accO rows q = qrow0 + rl, cols d = dblk*32 + l31
  const float inv = 1.0f / lrun;
  #pragma unroll
  for (int reg = 0; reg < 16; reg++) {
    const int rl = (reg & 3) + 8 * (reg >> 2) + (hi << 2);
    const float invr = __shfl(inv, rl);
    const int q = qrow0 + rl;
    const size_t base = ((size_t)(b * SEQLEN + q)) * DIMSZ + h * HD;
    Og[base + l31]      = f2bf(accO0[reg] * invr);
    Og[base + 32 + l31] = f2bf(accO1[reg] * invr);
  }
}

extern "C" void kernel_launch(void* const* d_in, const int* in_sizes, int n_in,
                              void* d_out, int out_size, void* d_ws, size_t ws_size,
                              hipStream_t stream)
{
  const float* x  = (const float*)d_in[0];
  const float* fc = (const float*)d_in[1];
  const float* fs = (const float*)d_in[2];
  const float* wq = (const float*)d_in[3];
  const float* wk = (const float*)d_in[4];
  const float* wv = (const float*)d_in[5];
  const float* wo = (const float*)d_in[6];
  float* out = (float*)d_out;
  char* ws = (char*)d_ws;

  unsigned short* xb    = (unsigned short*)(ws + 0);          // [4096][2048]
  unsigned short* wqkvb = (unsigned short*)(ws + 16777216);   // [3072][2048]
  unsigned short* wob   = (unsigned short*)(ws + 29360128);   // [2048][2048]
  unsigned short* Qb    = (unsigned short*)(ws + 62914560);   // [2][32][2048][64]
  unsigned short* Kb    = (unsigned short*)(ws + 79691776);   // [2][8][2048][64]
  unsigned short* Vtb   = (unsigned short*)(ws + 83886080);   // [2][8][64][2048]
  unsigned short* attnb = (unsigned short*)(ws + 88080384);   // [4096][2048]

  k_cvt_all<<<18432, 256, 0, stream>>>(x, wq, wk, wv, wo, xb, wqkvb, wob);

  dim3 g1(24, 32);   // N=3072/128, M=4096/128 — fused RoPE/Vt epilogue
  k_gemm_qkv<<<g1, 256, 0, stream>>>(xb, wqkvb, fc, fs, Qb, Kb, Vtb);

  k_attn<<<1024, 256, 0, stream>>>(Qb, Kb, Vtb, attnb);

  dim3 g2(16, 32);   // N=2048/128, M=4096/128
  k_gemm_bt<0><<<g2, 256, 0, stream>>>(attnb, wob, out, NROWS, DIMSZ, DIMSZ);
}

// Round 11
// 171.552 us; speedup vs baseline: 1.1012x; 1.1012x over previous
//
#include <hip/hip_runtime.h>

#define DIMSZ 2048
#define NH 32
#define NKV 8
#define HD 64
#define SEQLEN 2048
#define BATCH 2
#define NROWS (BATCH*SEQLEN)   // 4096
#define NQKVC 3072             // 2048 q + 512 k + 512 v

typedef __bf16 bf16x8 __attribute__((ext_vector_type(8)));
typedef __bf16 bf16x2 __attribute__((ext_vector_type(2)));
typedef float f32x4v __attribute__((ext_vector_type(4)));
typedef float f32x2v __attribute__((ext_vector_type(2)));
typedef float f32x16 __attribute__((ext_vector_type(16)));

__device__ __forceinline__ unsigned short f2bf(float f) {
  __bf16 h = (__bf16)f;
  union { __bf16 h; unsigned short u; } v; v.h = h; return v.u;
}
__device__ __forceinline__ unsigned int pk2bf(float lo, float hi) {
  f32x2v v; v[0] = lo; v[1] = hi;
  bf16x2 h = __builtin_convertvector(v, bf16x2);
  union { bf16x2 h; unsigned int u; } c; c.h = h; return c.u;
}
// XOR swizzle for LDS tiles with 128-byte rows.
__device__ __forceinline__ int swz128(int row, int colBytes) {
  return row * 128 + (colBytes ^ ((row & 7) << 4));
}

#define GLOAD16(g, l) __builtin_amdgcn_global_load_lds( \
    (const __attribute__((address_space(1))) unsigned int*)(g), \
    (__attribute__((address_space(3))) unsigned int*)(l), 16, 0, 0)

// ---------------- merged fp32 -> bf16 convert (x | wq|wk|wv | wo) ----------------
__global__ void k_cvt_all(const float* __restrict__ x,
                          const float* __restrict__ wq, const float* __restrict__ wk,
                          const float* __restrict__ wv, const float* __restrict__ wo,
                          unsigned short* __restrict__ xb,
                          unsigned short* __restrict__ wqkvb,
                          unsigned short* __restrict__ wob) {
  int i = blockIdx.x * 256 + threadIdx.x;   // 4,718,592 float4 total
  const float* s; unsigned short* d; int soff, doff;
  if (i < 2097152)        { s = x;  d = xb;    soff = i;           doff = i; }
  else if (i < 3145728)   { s = wq; d = wqkvb; soff = i - 2097152; doff = i - 2097152; }
  else if (i < 3407872)   { s = wk; d = wqkvb; soff = i - 3145728; doff = i - 2097152; }
  else if (i < 3670016)   { s = wv; d = wqkvb; soff = i - 3407872; doff = i - 2097152; }
  else                    { s = wo; d = wob;   soff = i - 3670016; doff = i - 3670016; }
  float4 v = reinterpret_cast<const float4*>(s)[soff];
  uint2 pk; pk.x = pk2bf(v.x, v.y); pk.y = pk2bf(v.z, v.w);
  reinterpret_cast<uint2*>(d)[doff] = pk;
}

// ---------------- QKV GEMM with fused RoPE / V-transpose epilogue ----------------
__global__ __launch_bounds__(256, 2) void k_gemm_qkv(
    const unsigned short* __restrict__ A,
    const unsigned short* __restrict__ B,
    const float* __restrict__ fc, const float* __restrict__ fs,
    unsigned short* __restrict__ Qb, unsigned short* __restrict__ Kb,
    unsigned short* __restrict__ Vt)
{
  constexpr int BK = 64, K = DIMSZ;
  __shared__ __attribute__((aligned(16))) unsigned short smA[128 * BK];
  __shared__ __attribute__((aligned(16))) unsigned short smB[128 * BK];
  const int tid = threadIdx.x;
  const int lane = tid & 63;
  const int wid = tid >> 6;
  const int lr = lane & 15, lg = lane >> 4;
  const int gx = gridDim.x;
  int lin = blockIdx.y * gx + blockIdx.x;
  const int cpx = (gx * gridDim.y) >> 3;
  lin = (lin & 7) * cpx + (lin >> 3);
  const int m0 = (lin / gx) * 128, n0 = (lin % gx) * 128;
  const int wr = (wid >> 1) * 64, wc = (wid & 1) * 64;

  f32x4v acc[4][4];
  #pragma unroll
  for (int i = 0; i < 4; i++)
    #pragma unroll
    for (int j = 0; j < 4; j++)
      acc[i][j] = f32x4v{0.f, 0.f, 0.f, 0.f};

  for (int k0 = 0; k0 < K; k0 += BK) {
    #pragma unroll
    for (int c = 0; c < 4; c++) {
      const int chunk = wid * 4 + c;
      const int idx = chunk * 64 + lane;
      const int row = idx >> 3, s = idx & 7;
      const int ks = (s ^ (row & 7)) * 8;
      GLOAD16(A + (size_t)(m0 + row) * K + k0 + ks, &smA[chunk * 512]);
      GLOAD16(B + (size_t)(n0 + row) * K + k0 + ks, &smB[chunk * 512]);
    }
    __syncthreads();
    #pragma unroll
    for (int ks = 0; ks < 2; ks++) {
      bf16x8 af[4], bfv[4];
      #pragma unroll
      for (int m = 0; m < 4; m++)
        af[m] = *reinterpret_cast<const bf16x8*>((char*)smA + swz128(wr + m * 16 + lr, ks * 64 + lg * 16));
      #pragma unroll
      for (int n = 0; n < 4; n++)
        bfv[n] = *reinterpret_cast<const bf16x8*>((char*)smB + swz128(wc + n * 16 + lr, ks * 64 + lg * 16));
      #pragma unroll
      for (int m = 0; m < 4; m++)
        #pragma unroll
        for (int n = 0; n < 4; n++)
          acc[m][n] = __builtin_amdgcn_mfma_f32_16x16x32_bf16(af[m], bfv[n], acc[m][n], 0, 0, 0);
    }
    __syncthreads();
  }
  const int bx = n0 >> 7;
  if (bx < 20) {
    const bool isQ = bx < 16;
    const float SCL = isQ ? 0.18033688011112043f : 1.0f;   // 0.125*log2(e) for Q
    #pragma unroll
    for (int n = 0; n < 4; n++) {
      const int col = n0 + wc + n * 16 + lr;
      const int d = col & 63;
      const int i = d >> 1;
      const float sgn = (d & 1) ? 1.0f : -1.0f;
      unsigned short* dst;
      if (isQ) dst = Qb + (size_t)(col >> 6) * (SEQLEN * HD) + d;
      else     dst = Kb + (size_t)((col - 2048) >> 6) * (SEQLEN * HD) + d;
      #pragma unroll
      for (int m = 0; m < 4; m++)
        #pragma unroll
        for (int r = 0; r < 4; r++) {
          const int row = m0 + wr + m * 16 + lg * 4 + r;
          const int s = row & (SEQLEN - 1), b = row >> 11;
          const float v = acc[m][n][r];
          const float p = __shfl_xor(v, 1);
          const float c = fc[s * 32 + i], sn = fs[s * 32 + i];
          const float o = (v * c + sgn * p * sn) * SCL;
          const size_t headStride = (size_t)(isQ ? NH : NKV) * SEQLEN * HD;
          dst[(size_t)b * headStride + (size_t)s * HD] = f2bf(o);
        }
    }
  } else {
    #pragma unroll
    for (int n = 0; n < 4; n++) {
      const int col = n0 + wc + n * 16 + lr;
      const int kvh = (col - 2560) >> 6, d = col & 63;
      #pragma unroll
      for (int m = 0; m < 4; m++) {
        const int row0 = m0 + wr + m * 16 + lg * 4;
        const int s0 = row0 & (SEQLEN - 1), b = row0 >> 11;
        uint2 pk;
        pk.x = pk2bf(acc[m][n][0], acc[m][n][1]);
        pk.y = pk2bf(acc[m][n][2], acc[m][n][3]);
        *reinterpret_cast<uint2*>(
            Vt + ((size_t)((b * NKV + kvh) * HD) + d) * SEQLEN + s0) = pk;
      }
    }
  }
}

// ---------------- GEMM: C[M][N] = A[M][K] * B[N][K]^T (O-projection) ----------------
template<int OUT_BF16>
__global__ __launch_bounds__(256, 2) void k_gemm_bt(
    const unsigned short* __restrict__ A,
    const unsigned short* __restrict__ B,
    void* __restrict__ Cv, int M, int N, int K)
{
  constexpr int BK = 64;
  __shared__ __attribute__((aligned(16))) unsigned short smA[128 * BK];
  __shared__ __attribute__((aligned(16))) unsigned short smB[128 * BK];
  const int tid = threadIdx.x;
  const int lane = tid & 63;
  const int wid = tid >> 6;
  const int lr = lane & 15, lg = lane >> 4;
  const int gx = gridDim.x;
  int lin = blockIdx.y * gx + blockIdx.x;
  const int cpx = (gx * gridDim.y) >> 3;
  lin = (lin & 7) * cpx + (lin >> 3);
  const int m0 = (lin / gx) * 128, n0 = (lin % gx) * 128;
  const int wr = (wid >> 1) * 64, wc = (wid & 1) * 64;

  f32x4v acc[4][4];
  #pragma unroll
  for (int i = 0; i < 4; i++)
    #pragma unroll
    for (int j = 0; j < 4; j++)
      acc[i][j] = f32x4v{0.f, 0.f, 0.f, 0.f};

  for (int k0 = 0; k0 < K; k0 += BK) {
    #pragma unroll
    for (int c = 0; c < 4; c++) {
      const int chunk = wid * 4 + c;
      const int idx = chunk * 64 + lane;
      const int row = idx >> 3, s = idx & 7;
      const int ks = (s ^ (row & 7)) * 8;
      GLOAD16(A + (size_t)(m0 + row) * K + k0 + ks, &smA[chunk * 512]);
      GLOAD16(B + (size_t)(n0 + row) * K + k0 + ks, &smB[chunk * 512]);
    }
    __syncthreads();
    #pragma unroll
    for (int ks = 0; ks < 2; ks++) {
      bf16x8 af[4], bfv[4];
      #pragma unroll
      for (int m = 0; m < 4; m++)
        af[m] = *reinterpret_cast<const bf16x8*>((char*)smA + swz128(wr + m * 16 + lr, ks * 64 + lg * 16));
      #pragma unroll
      for (int n = 0; n < 4; n++)
        bfv[n] = *reinterpret_cast<const bf16x8*>((char*)smB + swz128(wc + n * 16 + lr, ks * 64 + lg * 16));
      #pragma unroll
      for (int m = 0; m < 4; m++)
        #pragma unroll
        for (int n = 0; n < 4; n++)
          acc[m][n] = __builtin_amdgcn_mfma_f32_16x16x32_bf16(af[m], bfv[n], acc[m][n], 0, 0, 0);
    }
    __syncthreads();
  }
  #pragma unroll
  for (int m = 0; m < 4; m++)
    #pragma unroll
    for (int n = 0; n < 4; n++)
      #pragma unroll
      for (int r = 0; r < 4; r++) {
        const size_t row = m0 + wr + m * 16 + lg * 4 + r;
        const size_t col = n0 + wc + n * 16 + lr;
        if (OUT_BF16) ((unsigned short*)Cv)[row * N + col] = f2bf(acc[m][n][r]);
        else          ((float*)Cv)[row * N + col] = acc[m][n][r];
      }
}

// ---------------- flash attention: 32x32 MFMA, 8 waves x 32 q-rows ----------------
// Round 11: 512-thread blocks (8 waves, 256-row q-tile), 512 blocks -> 2
// blocks/CU = 16 waves/CU = 4 waves/SIMD (2x round 8) to hide the serial
// softmax chain. Unpaired q-tiles, LPT order: longest (qt=7) dispatched first.
// 2 KV panels pinned per XCD (~4.2MB ~ L2).
__global__ __launch_bounds__(512, 2) void k_attn(
    const unsigned short* __restrict__ Qg,   // [B][NH][S][HD], scaled 0.125*log2e
    const unsigned short* __restrict__ Kg,   // [B][NKV][S][HD]
    const unsigned short* __restrict__ Vt,   // [B][NKV][HD][S]
    unsigned short* __restrict__ Og)         // [B*S][NH*HD]
{
  constexpr int KVB = 64;
  __shared__ __attribute__((aligned(16))) unsigned short sK0[KVB * HD];
  __shared__ __attribute__((aligned(16))) unsigned short sK1[KVB * HD];
  __shared__ __attribute__((aligned(16))) unsigned short sV0[HD * KVB];
  __shared__ __attribute__((aligned(16))) unsigned short sV1[HD * KVB];
  const int tid = threadIdx.x;
  const int lane = tid & 63, wid = tid >> 6;       // 8 waves
  const int l31 = lane & 31, hi = lane >> 5;
  // LPT + XCD mapping: g&7 = XCD; qt descends with dispatch order.
  const int g = blockIdx.x;                        // 512 blocks
  const int c = g >> 3;                            // 0..63 per XCD slot
  const int qt = 7 - (c >> 3);                     // longest first
  const int rem = c & 7;
  const int p = (g & 7) * 2 + (rem >> 2);          // panel 0..15 (2 per XCD)
  const int kvh = p & 7, b = p >> 3;
  const int h = kvh * 4 + (rem & 3);
  const unsigned short* Qp = Qg + ((size_t)(b * NH + h) * SEQLEN) * HD;
  const unsigned short* Kp = Kg + ((size_t)(b * NKV + kvh) * SEQLEN) * HD;
  const unsigned short* Vp = Vt + ((size_t)(b * NKV + kvh) * HD) * SEQLEN;

  // staging: 8 chunks of 1KB per 8KB tile; wave wid owns chunk wid
  const int sidx = wid * 64 + lane;
  const int srow = sidx >> 3;
  const int scol = ((sidx & 7) ^ (srow & 7)) * 8;

  const int qrow0 = qt * 256 + wid * 32;
  const int qg = qrow0 + l31;                      // this lane's q-row
  bf16x8 aq[4];                                    // Q B-frags: k-slice ks*16+hi*8
  #pragma unroll
  for (int ks = 0; ks < 4; ks++)
    aq[ks] = *reinterpret_cast<const bf16x8*>(Qp + (size_t)qg * HD + ks * 16 + hi * 8);

  f32x16 accO0, accO1;
  #pragma unroll
  for (int ii = 0; ii < 16; ii++) { accO0[ii] = 0.f; accO1[ii] = 0.f; }
  float mrun = -3.0e38f, lrun = 0.f;               // log2-domain state for q=qg

  auto compute = [&](int kv0, auto& sKb, auto& sVb) {
    if (kv0 > qrow0 + 31) return;
    f32x16 S0, S1;
    #pragma unroll
    for (int ii = 0; ii < 16; ii++) { S0[ii] = 0.f; S1[ii] = 0.f; }
    __builtin_amdgcn_s_setprio(1);
    #pragma unroll
    for (int ks = 0; ks < 4; ks++) {
      bf16x8 ak0 = *reinterpret_cast<const bf16x8*>((char*)sKb + swz128(l31,      ks * 32 + hi * 16));
      bf16x8 ak1 = *reinterpret_cast<const bf16x8*>((char*)sKb + swz128(32 + l31, ks * 32 + hi * 16));
      S0 = __builtin_amdgcn_mfma_f32_32x32x16_bf16(ak0, aq[ks], S0, 0, 0, 0);
      S1 = __builtin_amdgcn_mfma_f32_32x32x16_bf16(ak1, aq[ks], S1, 0, 0, 0);
    }
    __builtin_amdgcn_s_setprio(0);
    if (kv0 + KVB - 1 > qrow0) {                   // boundary tile: causal mask
      #pragma unroll
      for (int reg = 0; reg < 16; reg++) {
        const int rl = (reg & 3) + 8 * (reg >> 2) + (hi << 2);
        if (kv0 + rl > qg)      S0[reg] = -1.0e30f;
        if (kv0 + 32 + rl > qg) S1[reg] = -1.0e30f;
      }
    }
    // row max: pairwise tree (depth 5) + 1 cross-half exchange
    float t16[16];
    #pragma unroll
    for (int ii = 0; ii < 16; ii++) t16[ii] = fmaxf(S0[ii], S1[ii]);
    float t8[8];
    #pragma unroll
    for (int ii = 0; ii < 8; ii++) t8[ii] = fmaxf(t16[ii], t16[ii + 8]);
    float t4[4];
    #pragma unroll
    for (int ii = 0; ii < 4; ii++) t4[ii] = fmaxf(t8[ii], t8[ii + 4]);
    float tm = fmaxf(fmaxf(t4[0], t4[1]), fmaxf(t4[2], t4[3]));
    tm = fmaxf(tm, __shfl_xor(tm, 32));
    const float mo = mrun;
    const bool defer = __all(tm <= mo + 8.0f);     // T13, log2 domain
    const float mn = defer ? mo : fmaxf(mo, tm);
    #pragma unroll
    for (int ii = 0; ii < 16; ii++) {
      S0[ii] = __builtin_amdgcn_exp2f(S0[ii] - mn);
      S1[ii] = __builtin_amdgcn_exp2f(S1[ii] - mn);
    }
    // row sum: pairwise tree
    float u16[16];
    #pragma unroll
    for (int ii = 0; ii < 16; ii++) u16[ii] = S0[ii] + S1[ii];
    float u8[8];
    #pragma unroll
    for (int ii = 0; ii < 8; ii++) u8[ii] = u16[ii] + u16[ii + 8];
    float u4[4];
    #pragma unroll
    for (int ii = 0; ii < 4; ii++) u4[ii] = u8[ii] + u8[ii + 4];
    float rs = (u4[0] + u4[1]) + (u4[2] + u4[3]);
    rs += __shfl_xor(rs, 32);
    if (defer) {
      lrun += rs;
    } else {
      const float sc = __builtin_amdgcn_exp2f(mo - mn);
      mrun = mn;
      lrun = lrun * sc + rs;
      #pragma unroll
      for (int reg = 0; reg < 16; reg++) {
        const int rl = (reg & 3) + 8 * (reg >> 2) + (hi << 2);
        const float scr = __shfl(sc, rl);
        accO0[reg] *= scr; accO1[reg] *= scr;
      }
    }
    // PV: build A-frags in-register (T12) and accumulate O[q][d]
    __builtin_amdgcn_s_setprio(1);
    #define PVSTEP(S16, G, CB) do {                                          \
      unsigned a0 = pk2bf(S16[(G)+0], S16[(G)+1]);                           \
      unsigned a1 = pk2bf(S16[(G)+2], S16[(G)+3]);                           \
      unsigned b0 = pk2bf(S16[(G)+4], S16[(G)+5]);                           \
      unsigned b1 = pk2bf(S16[(G)+6], S16[(G)+7]);                           \
      unsigned s0 = hi ? a0 : b0, s1 = hi ? a1 : b1;                         \
      unsigned r0 = __shfl_xor((int)s0, 32), r1 = __shfl_xor((int)s1, 32);   \
      union { unsigned u[4]; bf16x8 v; } pf;                                 \
      pf.u[0] = hi ? r0 : a0; pf.u[1] = hi ? r1 : a1;                        \
      pf.u[2] = hi ? b0 : r0; pf.u[3] = hi ? b1 : r1;                        \
      bf16x8 bv0 = *reinterpret_cast<const bf16x8*>((char*)sVb + swz128(l31,      (CB))); \
      bf16x8 bv1 = *reinterpret_cast<const bf16x8*>((char*)sVb + swz128(32 + l31, (CB))); \
      accO0 = __builtin_amdgcn_mfma_f32_32x32x16_bf16(pf.v, bv0, accO0, 0, 0, 0); \
      accO1 = __builtin_amdgcn_mfma_f32_32x32x16_bf16(pf.v, bv1, accO1, 0, 0, 0); \
    } while (0)
    PVSTEP(S0, 0,  0  + hi * 16);
    PVSTEP(S0, 8,  32 + hi * 16);
    PVSTEP(S1, 0,  64 + hi * 16);
    PVSTEP(S1, 8,  96 + hi * 16);
    #undef PVSTEP
    __builtin_amdgcn_s_setprio(0);
  };

  const int nt = (qt + 1) * 4;    // multiple of 4 -> even
  GLOAD16(Kp + (size_t)srow * HD + scol, &sK0[wid * 512]);
  GLOAD16(Vp + (size_t)srow * SEQLEN + scol, &sV0[wid * 512]);
  __syncthreads();
  for (int t = 0; t < nt; t += 2) {
    {
      const int kn = (t + 1) * KVB;
      GLOAD16(Kp + (size_t)(kn + srow) * HD + scol, &sK1[wid * 512]);
      GLOAD16(Vp + (size_t)srow * SEQLEN + kn + scol, &sV1[wid * 512]);
    }
    compute(t * KVB, sK0, sV0);
    __syncthreads();
    if (t + 2 < nt) {
      const int kn = (t + 2) * KVB;
      GLOAD16(Kp + (size_t)(kn + srow) * HD + scol, &sK0[wid * 512]);
      GLOAD16(Vp + (size_t)srow * SEQLEN + kn + scol, &sV0[wid * 512]);
    }
    compute((t + 1) * KVB, sK1, sV1);
    __syncthreads();
  }
  // normalize + store: accO rows q = qrow0 + rl, cols d = dblk*32 + l31
  const float inv = 1.0f / lrun;
  #pragma unroll
  for (int reg = 0; reg < 16; reg++) {
    const int rl = (reg & 3) + 8 * (reg >> 2) + (hi << 2);
    const float invr = __shfl(inv, rl);
    const int q = qrow0 + rl;
    const size_t base = ((size_t)(b * SEQLEN + q)) * DIMSZ + h * HD;
    Og[base + l31]      = f2bf(accO0[reg] * invr);
    Og[base + 32 + l31] = f2bf(accO1[reg] * invr);
  }
}

extern "C" void kernel_launch(void* const* d_in, const int* in_sizes, int n_in,
                              void* d_out, int out_size, void* d_ws, size_t ws_size,
                              hipStream_t stream)
{
  const float* x  = (const float*)d_in[0];
  const float* fc = (const float*)d_in[1];
  const float* fs = (const float*)d_in[2];
  const float* wq = (const float*)d_in[3];
  const float* wk = (const float*)d_in[4];
  const float* wv = (const float*)d_in[5];
  const float* wo = (const float*)d_in[6];
  float* out = (float*)d_out;
  char* ws = (char*)d_ws;

  unsigned short* xb    = (unsigned short*)(ws + 0);          // [4096][2048]
  unsigned short* wqkvb = (unsigned short*)(ws + 16777216);   // [3072][2048]
  unsigned short* wob   = (unsigned short*)(ws + 29360128);   // [2048][2048]
  unsigned short* Qb    = (unsigned short*)(ws + 62914560);   // [2][32][2048][64]
  unsigned short* Kb    = (unsigned short*)(ws + 79691776);   // [2][8][2048][64]
  unsigned short* Vtb   = (unsigned short*)(ws + 83886080);   // [2][8][64][2048]
  unsigned short* attnb = (unsigned short*)(ws + 88080384);   // [4096][2048]

  k_cvt_all<<<18432, 256, 0, stream>>>(x, wq, wk, wv, wo, xb, wqkvb, wob);

  dim3 g1(24, 32);   // N=3072/128, M=4096/128 — fused RoPE/Vt epilogue
  k_gemm_qkv<<<g1, 256, 0, stream>>>(xb, wqkvb, fc, fs, Qb, Kb, Vtb);

  k_attn<<<512, 512, 0, stream>>>(Qb, Kb, Vtb, attnb);

  dim3 g2(16, 32);   // N=2048/128, M=4096/128
  k_gemm_bt<0><<<g2, 256, 0, stream>>>(attnb, wob, out, NROWS, DIMSZ, DIMSZ);
}

// Round 12
// 171.367 us; speedup vs baseline: 1.1024x; 1.0011x over previous
//
#include <hip/hip_runtime.h>

#define DIMSZ 2048
#define NH 32
#define NKV 8
#define HD 64
#define SEQLEN 2048
#define BATCH 2
#define NROWS (BATCH*SEQLEN)   // 4096
#define NQKVC 3072             // 2048 q + 512 k + 512 v

typedef __bf16 bf16x8 __attribute__((ext_vector_type(8)));
typedef __bf16 bf16x2 __attribute__((ext_vector_type(2)));
typedef float f32x4v __attribute__((ext_vector_type(4)));
typedef float f32x2v __attribute__((ext_vector_type(2)));
typedef float f32x16 __attribute__((ext_vector_type(16)));

__device__ __forceinline__ unsigned short f2bf(float f) {
  __bf16 h = (__bf16)f;
  union { __bf16 h; unsigned short u; } v; v.h = h; return v.u;
}
__device__ __forceinline__ unsigned int pk2bf(float lo, float hi) {
  f32x2v v; v[0] = lo; v[1] = hi;
  bf16x2 h = __builtin_convertvector(v, bf16x2);
  union { bf16x2 h; unsigned int u; } c; c.h = h; return c.u;
}
// XOR swizzle for LDS tiles with 128-byte rows.
__device__ __forceinline__ int swz128(int row, int colBytes) {
  return row * 128 + (colBytes ^ ((row & 7) << 4));
}

#define GLOAD16(g, l) __builtin_amdgcn_global_load_lds( \
    (const __attribute__((address_space(1))) unsigned int*)(g), \
    (__attribute__((address_space(3))) unsigned int*)(l), 16, 0, 0)

// ---------------- merged fp32 -> bf16 convert (x | wq|wk|wv | wo) ----------------
__global__ void k_cvt_all(const float* __restrict__ x,
                          const float* __restrict__ wq, const float* __restrict__ wk,
                          const float* __restrict__ wv, const float* __restrict__ wo,
                          unsigned short* __restrict__ xb,
                          unsigned short* __restrict__ wqkvb,
                          unsigned short* __restrict__ wob) {
  int i = blockIdx.x * 256 + threadIdx.x;   // 4,718,592 float4 total
  const float* s; unsigned short* d; int soff, doff;
  if (i < 2097152)        { s = x;  d = xb;    soff = i;           doff = i; }
  else if (i < 3145728)   { s = wq; d = wqkvb; soff = i - 2097152; doff = i - 2097152; }
  else if (i < 3407872)   { s = wk; d = wqkvb; soff = i - 3145728; doff = i - 2097152; }
  else if (i < 3670016)   { s = wv; d = wqkvb; soff = i - 3407872; doff = i - 2097152; }
  else                    { s = wo; d = wob;   soff = i - 3670016; doff = i - 3670016; }
  float4 v = reinterpret_cast<const float4*>(s)[soff];
  uint2 pk; pk.x = pk2bf(v.x, v.y); pk.y = pk2bf(v.z, v.w);
  reinterpret_cast<uint2*>(d)[doff] = pk;
}

// ---------------- QKV GEMM with fused RoPE / V-transpose epilogue ----------------
__global__ __launch_bounds__(256, 2) void k_gemm_qkv(
    const unsigned short* __restrict__ A,
    const unsigned short* __restrict__ B,
    const float* __restrict__ fc, const float* __restrict__ fs,
    unsigned short* __restrict__ Qb, unsigned short* __restrict__ Kb,
    unsigned short* __restrict__ Vt)
{
  constexpr int BK = 64, K = DIMSZ;
  __shared__ __attribute__((aligned(16))) unsigned short smA[128 * BK];
  __shared__ __attribute__((aligned(16))) unsigned short smB[128 * BK];
  const int tid = threadIdx.x;
  const int lane = tid & 63;
  const int wid = tid >> 6;
  const int lr = lane & 15, lg = lane >> 4;
  const int gx = gridDim.x;
  int lin = blockIdx.y * gx + blockIdx.x;
  const int cpx = (gx * gridDim.y) >> 3;
  lin = (lin & 7) * cpx + (lin >> 3);
  const int m0 = (lin / gx) * 128, n0 = (lin % gx) * 128;
  const int wr = (wid >> 1) * 64, wc = (wid & 1) * 64;

  f32x4v acc[4][4];
  #pragma unroll
  for (int i = 0; i < 4; i++)
    #pragma unroll
    for (int j = 0; j < 4; j++)
      acc[i][j] = f32x4v{0.f, 0.f, 0.f, 0.f};

  for (int k0 = 0; k0 < K; k0 += BK) {
    #pragma unroll
    for (int c = 0; c < 4; c++) {
      const int chunk = wid * 4 + c;
      const int idx = chunk * 64 + lane;
      const int row = idx >> 3, s = idx & 7;
      const int ks = (s ^ (row & 7)) * 8;
      GLOAD16(A + (size_t)(m0 + row) * K + k0 + ks, &smA[chunk * 512]);
      GLOAD16(B + (size_t)(n0 + row) * K + k0 + ks, &smB[chunk * 512]);
    }
    __syncthreads();
    #pragma unroll
    for (int ks = 0; ks < 2; ks++) {
      bf16x8 af[4], bfv[4];
      #pragma unroll
      for (int m = 0; m < 4; m++)
        af[m] = *reinterpret_cast<const bf16x8*>((char*)smA + swz128(wr + m * 16 + lr, ks * 64 + lg * 16));
      #pragma unroll
      for (int n = 0; n < 4; n++)
        bfv[n] = *reinterpret_cast<const bf16x8*>((char*)smB + swz128(wc + n * 16 + lr, ks * 64 + lg * 16));
      #pragma unroll
      for (int m = 0; m < 4; m++)
        #pragma unroll
        for (int n = 0; n < 4; n++)
          acc[m][n] = __builtin_amdgcn_mfma_f32_16x16x32_bf16(af[m], bfv[n], acc[m][n], 0, 0, 0);
    }
    __syncthreads();
  }
  const int bx = n0 >> 7;
  if (bx < 20) {
    const bool isQ = bx < 16;
    const float SCL = isQ ? 0.18033688011112043f : 1.0f;   // 0.125*log2(e) for Q
    #pragma unroll
    for (int n = 0; n < 4; n++) {
      const int col = n0 + wc + n * 16 + lr;
      const int d = col & 63;
      const int i = d >> 1;
      const float sgn = (d & 1) ? 1.0f : -1.0f;
      unsigned short* dst;
      if (isQ) dst = Qb + (size_t)(col >> 6) * (SEQLEN * HD) + d;
      else     dst = Kb + (size_t)((col - 2048) >> 6) * (SEQLEN * HD) + d;
      #pragma unroll
      for (int m = 0; m < 4; m++)
        #pragma unroll
        for (int r = 0; r < 4; r++) {
          const int row = m0 + wr + m * 16 + lg * 4 + r;
          const int s = row & (SEQLEN - 1), b = row >> 11;
          const float v = acc[m][n][r];
          const float p = __shfl_xor(v, 1);
          const float c = fc[s * 32 + i], sn = fs[s * 32 + i];
          const float o = (v * c + sgn * p * sn) * SCL;
          const size_t headStride = (size_t)(isQ ? NH : NKV) * SEQLEN * HD;
          dst[(size_t)b * headStride + (size_t)s * HD] = f2bf(o);
        }
    }
  } else {
    #pragma unroll
    for (int n = 0; n < 4; n++) {
      const int col = n0 + wc + n * 16 + lr;
      const int kvh = (col - 2560) >> 6, d = col & 63;
      #pragma unroll
      for (int m = 0; m < 4; m++) {
        const int row0 = m0 + wr + m * 16 + lg * 4;
        const int s0 = row0 & (SEQLEN - 1), b = row0 >> 11;
        uint2 pk;
        pk.x = pk2bf(acc[m][n][0], acc[m][n][1]);
        pk.y = pk2bf(acc[m][n][2], acc[m][n][3]);
        *reinterpret_cast<uint2*>(
            Vt + ((size_t)((b * NKV + kvh) * HD) + d) * SEQLEN + s0) = pk;
      }
    }
  }
}

// ---------------- GEMM: C[M][N] = A[M][K] * B[N][K]^T (O-projection) ----------------
template<int OUT_BF16>
__global__ __launch_bounds__(256, 2) void k_gemm_bt(
    const unsigned short* __restrict__ A,
    const unsigned short* __restrict__ B,
    void* __restrict__ Cv, int M, int N, int K)
{
  constexpr int BK = 64;
  __shared__ __attribute__((aligned(16))) unsigned short smA[128 * BK];
  __shared__ __attribute__((aligned(16))) unsigned short smB[128 * BK];
  const int tid = threadIdx.x;
  const int lane = tid & 63;
  const int wid = tid >> 6;
  const int lr = lane & 15, lg = lane >> 4;
  const int gx = gridDim.x;
  int lin = blockIdx.y * gx + blockIdx.x;
  const int cpx = (gx * gridDim.y) >> 3;
  lin = (lin & 7) * cpx + (lin >> 3);
  const int m0 = (lin / gx) * 128, n0 = (lin % gx) * 128;
  const int wr = (wid >> 1) * 64, wc = (wid & 1) * 64;

  f32x4v acc[4][4];
  #pragma unroll
  for (int i = 0; i < 4; i++)
    #pragma unroll
    for (int j = 0; j < 4; j++)
      acc[i][j] = f32x4v{0.f, 0.f, 0.f, 0.f};

  for (int k0 = 0; k0 < K; k0 += BK) {
    #pragma unroll
    for (int c = 0; c < 4; c++) {
      const int chunk = wid * 4 + c;
      const int idx = chunk * 64 + lane;
      const int row = idx >> 3, s = idx & 7;
      const int ks = (s ^ (row & 7)) * 8;
      GLOAD16(A + (size_t)(m0 + row) * K + k0 + ks, &smA[chunk * 512]);
      GLOAD16(B + (size_t)(n0 + row) * K + k0 + ks, &smB[chunk * 512]);
    }
    __syncthreads();
    #pragma unroll
    for (int ks = 0; ks < 2; ks++) {
      bf16x8 af[4], bfv[4];
      #pragma unroll
      for (int m = 0; m < 4; m++)
        af[m] = *reinterpret_cast<const bf16x8*>((char*)smA + swz128(wr + m * 16 + lr, ks * 64 + lg * 16));
      #pragma unroll
      for (int n = 0; n < 4; n++)
        bfv[n] = *reinterpret_cast<const bf16x8*>((char*)smB + swz128(wc + n * 16 + lr, ks * 64 + lg * 16));
      #pragma unroll
      for (int m = 0; m < 4; m++)
        #pragma unroll
        for (int n = 0; n < 4; n++)
          acc[m][n] = __builtin_amdgcn_mfma_f32_16x16x32_bf16(af[m], bfv[n], acc[m][n], 0, 0, 0);
    }
    __syncthreads();
  }
  #pragma unroll
  for (int m = 0; m < 4; m++)
    #pragma unroll
    for (int n = 0; n < 4; n++)
      #pragma unroll
      for (int r = 0; r < 4; r++) {
        const size_t row = m0 + wr + m * 16 + lg * 4 + r;
        const size_t col = n0 + wc + n * 16 + lr;
        if (OUT_BF16) ((unsigned short*)Cv)[row * N + col] = f2bf(acc[m][n][r]);
        else          ((float*)Cv)[row * N + col] = acc[m][n][r];
      }
}

// ---------------- flash attention: 32x32 MFMA, 4 waves, T15 pipelined ----------------
// Round 12: software-pipeline by one tile. Iteration t executes QK(t+1) (pure
// MFMA) BEFORE softmax(t)+PV(t) so the QK MFMA cluster overlaps the previous
// tile's softmax VALU/trans chain (separate pipes, m114). K staged 2 tiles
// ahead, V 1 tile ahead (time-split dbufs, 4x8KB) -> depth-1 prefetch stays
// fully overlapped under plain __syncthreads. Unroll-2 gives static buffer/S
// names (rule #20). Compute math identical to round 8/11 (verified).
__global__ __launch_bounds__(256, 2) void k_attn(
    const unsigned short* __restrict__ Qg,   // [B][NH][S][HD], scaled 0.125*log2e
    const unsigned short* __restrict__ Kg,   // [B][NKV][S][HD]
    const unsigned short* __restrict__ Vt,   // [B][NKV][HD][S]
    unsigned short* __restrict__ Og)         // [B*S][NH*HD]
{
  constexpr int KVB = 64;
  __shared__ __attribute__((aligned(16))) unsigned short sK0[KVB * HD];
  __shared__ __attribute__((aligned(16))) unsigned short sK1[KVB * HD];
  __shared__ __attribute__((aligned(16))) unsigned short sV0[HD * KVB];
  __shared__ __attribute__((aligned(16))) unsigned short sV1[HD * KVB];
  const int tid = threadIdx.x;
  const int lane = tid & 63, wid = tid >> 6;       // 4 waves
  const int l31 = lane & 31, hi = lane >> 5;
  // XCD swizzle: each XCD owns one kv-head panel (round-8 mapping)
  const int orig = blockIdx.x;                     // 512 blocks
  const int w = (orig & 7) * 64 + (orig >> 3);
  const int kvh = w >> 6;
  const int b = (w >> 5) & 1;
  const int h = kvh * 4 + ((w >> 3) & 3);
  const int qp = w & 7;
  const unsigned short* Qp = Qg + ((size_t)(b * NH + h) * SEQLEN) * HD;
  const unsigned short* Kp = Kg + ((size_t)(b * NKV + kvh) * SEQLEN) * HD;
  const unsigned short* Vp = Vt + ((size_t)(b * NKV + kvh) * HD) * SEQLEN;

  // staging: 8 chunks of 1KB per 8KB tile; wave wid owns chunks 2wid, 2wid+1
  int srow[2], scol[2];
  #pragma unroll
  for (int cc = 0; cc < 2; cc++) {
    const int idx = (wid * 2 + cc) * 64 + lane;
    srow[cc] = idx >> 3;
    scol[cc] = ((idx & 7) ^ (srow[cc] & 7)) * 8;
  }

  for (int phase = 0; phase < 2; phase++) {
    const int qt = phase ? (15 - qp) : qp;
    const int qrow0 = qt * 128 + wid * 32;
    const int qg = qrow0 + l31;
    bf16x8 aq[4];
    #pragma unroll
    for (int ks = 0; ks < 4; ks++)
      aq[ks] = *reinterpret_cast<const bf16x8*>(Qp + (size_t)qg * HD + ks * 16 + hi * 8);

    f32x16 accO0, accO1;
    #pragma unroll
    for (int ii = 0; ii < 16; ii++) { accO0[ii] = 0.f; accO1[ii] = 0.f; }
    float mrun = -3.0e38f, lrun = 0.f;

    auto STAGE_K = [&](int t, unsigned short* buf) {
      #pragma unroll
      for (int cc = 0; cc < 2; cc++)
        GLOAD16(Kp + (size_t)(t * KVB + srow[cc]) * HD + scol[cc], &buf[(wid * 2 + cc) * 512]);
    };
    auto STAGE_V = [&](int t, unsigned short* buf) {
      #pragma unroll
      for (int cc = 0; cc < 2; cc++)
        GLOAD16(Vp + (size_t)srow[cc] * SEQLEN + t * KVB + scol[cc], &buf[(wid * 2 + cc) * 512]);
    };
    auto QK = [&](int kv0, const unsigned short* bK, f32x16& S0, f32x16& S1) {
      if (kv0 > qrow0 + 31) return;
      #pragma unroll
      for (int ii = 0; ii < 16; ii++) { S0[ii] = 0.f; S1[ii] = 0.f; }
      __builtin_amdgcn_s_setprio(1);
      #pragma unroll
      for (int ks = 0; ks < 4; ks++) {
        bf16x8 ak0 = *reinterpret_cast<const bf16x8*>((const char*)bK + swz128(l31,      ks * 32 + hi * 16));
        bf16x8 ak1 = *reinterpret_cast<const bf16x8*>((const char*)bK + swz128(32 + l31, ks * 32 + hi * 16));
        S0 = __builtin_amdgcn_mfma_f32_32x32x16_bf16(ak0, aq[ks], S0, 0, 0, 0);
        S1 = __builtin_amdgcn_mfma_f32_32x32x16_bf16(ak1, aq[ks], S1, 0, 0, 0);
      }
      __builtin_amdgcn_s_setprio(0);
    };
    auto SMPV = [&](int kv0, const unsigned short* bV, f32x16& S0, f32x16& S1) {
      if (kv0 > qrow0 + 31) return;
      if (kv0 + KVB - 1 > qrow0) {                 // boundary tile: causal mask
        #pragma unroll
        for (int reg = 0; reg < 16; reg++) {
          const int rl = (reg & 3) + 8 * (reg >> 2) + (hi << 2);
          if (kv0 + rl > qg)      S0[reg] = -1.0e30f;
          if (kv0 + 32 + rl > qg) S1[reg] = -1.0e30f;
        }
      }
      float t16[16];
      #pragma unroll
      for (int ii = 0; ii < 16; ii++) t16[ii] = fmaxf(S0[ii], S1[ii]);
      float t8[8];
      #pragma unroll
      for (int ii = 0; ii < 8; ii++) t8[ii] = fmaxf(t16[ii], t16[ii + 8]);
      float t4[4];
      #pragma unroll
      for (int ii = 0; ii < 4; ii++) t4[ii] = fmaxf(t8[ii], t8[ii + 4]);
      float tm = fmaxf(fmaxf(t4[0], t4[1]), fmaxf(t4[2], t4[3]));
      tm = fmaxf(tm, __shfl_xor(tm, 32));
      const float mo = mrun;
      const bool defer = __all(tm <= mo + 8.0f);   // T13, log2 domain
      const float mn = defer ? mo : fmaxf(mo, tm);
      #pragma unroll
      for (int ii = 0; ii < 16; ii++) {
        S0[ii] = __builtin_amdgcn_exp2f(S0[ii] - mn);
        S1[ii] = __builtin_amdgcn_exp2f(S1[ii] - mn);
      }
      float u16[16];
      #pragma unroll
      for (int ii = 0; ii < 16; ii++) u16[ii] = S0[ii] + S1[ii];
      float u8[8];
      #pragma unroll
      for (int ii = 0; ii < 8; ii++) u8[ii] = u16[ii] + u16[ii + 8];
      float u4[4];
      #pragma unroll
      for (int ii = 0; ii < 4; ii++) u4[ii] = u8[ii] + u8[ii + 4];
      float rs = (u4[0] + u4[1]) + (u4[2] + u4[3]);
      rs += __shfl_xor(rs, 32);
      if (defer) {
        lrun += rs;
      } else {
        const float sc = __builtin_amdgcn_exp2f(mo - mn);
        mrun = mn;
        lrun = lrun * sc + rs;
        #pragma unroll
        for (int reg = 0; reg < 16; reg++) {
          const int rl = (reg & 3) + 8 * (reg >> 2) + (hi << 2);
          const float scr = __shfl(sc, rl);
          accO0[reg] *= scr; accO1[reg] *= scr;
        }
      }
      __builtin_amdgcn_s_setprio(1);
      #define PVSTEP(S16, G, CB) do {                                          \
        unsigned a0 = pk2bf(S16[(G)+0], S16[(G)+1]);                           \
        unsigned a1 = pk2bf(S16[(G)+2], S16[(G)+3]);                           \
        unsigned b0 = pk2bf(S16[(G)+4], S16[(G)+5]);                           \
        unsigned b1 = pk2bf(S16[(G)+6], S16[(G)+7]);                           \
        unsigned s0 = hi ? a0 : b0, s1 = hi ? a1 : b1;                         \
        unsigned r0 = __shfl_xor((int)s0, 32), r1 = __shfl_xor((int)s1, 32);   \
        union { unsigned u[4]; bf16x8 v; } pf;                                 \
        pf.u[0] = hi ? r0 : a0; pf.u[1] = hi ? r1 : a1;                        \
        pf.u[2] = hi ? b0 : r0; pf.u[3] = hi ? b1 : r1;                        \
        bf16x8 bv0 = *reinterpret_cast<const bf16x8*>((const char*)bV + swz128(l31,      (CB))); \
        bf16x8 bv1 = *reinterpret_cast<const bf16x8*>((const char*)bV + swz128(32 + l31, (CB))); \
        accO0 = __builtin_amdgcn_mfma_f32_32x32x16_bf16(pf.v, bv0, accO0, 0, 0, 0); \
        accO1 = __builtin_amdgcn_mfma_f32_32x32x16_bf16(pf.v, bv1, accO1, 0, 0, 0); \
      } while (0)
      PVSTEP(S0, 0,  0  + hi * 16);
      PVSTEP(S0, 8,  32 + hi * 16);
      PVSTEP(S1, 0,  64 + hi * 16);
      PVSTEP(S1, 8,  96 + hi * 16);
      #undef PVSTEP
      __builtin_amdgcn_s_setprio(0);
    };

    const int nt = qt * 2 + 2;    // always even, >= 2
    f32x16 Sa0, Sa1, Sb0, Sb1;
    // prologue: tile0 K/V staged; K1 in flight; QK(0)
    STAGE_K(0, sK0);
    STAGE_V(0, sV0);
    __syncthreads();
    STAGE_K(1, sK1);
    QK(0, sK0, Sa0, Sa1);
    for (int t = 0; t < nt; t += 2) {
      // even half-iter: drains STAGE_K(t+1); stage K(t+2)->sK0, V(t+1)->sV1;
      // QK(t+1) overlaps SMPV(t)
      __syncthreads();
      if (t + 2 < nt) STAGE_K(t + 2, sK0);
      STAGE_V(t + 1, sV1);
      QK((t + 1) * KVB, sK1, Sb0, Sb1);
      SMPV(t * KVB, sV0, Sa0, Sa1);
      // odd half-iter
      __syncthreads();
      if (t + 3 < nt) STAGE_K(t + 3, sK1);
      if (t + 2 < nt) { STAGE_V(t + 2, sV0); QK((t + 2) * KVB, sK0, Sa0, Sa1); }
      SMPV((t + 1) * KVB, sV1, Sb0, Sb1);
    }
    // normalize + store
    const float inv = 1.0f / lrun;
    #pragma unroll
    for (int reg = 0; reg < 16; reg++) {
      const int rl = (reg & 3) + 8 * (reg >> 2) + (hi << 2);
      const float invr = __shfl(inv, rl);
      const int q = qrow0 + rl;
      const size_t base = ((size_t)(b * SEQLEN + q)) * DIMSZ + h * HD;
      Og[base + l31]      = f2bf(accO0[reg] * invr);
      Og[base + 32 + l31] = f2bf(accO1[reg] * invr);
    }
    // phase-1 prologue writes sK0/sV0: last phase-0 readers of those buffers
    // finished before the final in-loop barrier (audited); sV1 (read by the
    // tail SMPV) is not written until after the next barrier.
  }
}

extern "C" void kernel_launch(void* const* d_in, const int* in_sizes, int n_in,
                              void* d_out, int out_size, void* d_ws, size_t ws_size,
                              hipStream_t stream)
{
  const float* x  = (const float*)d_in[0];
  const float* fc = (const float*)d_in[1];
  const float* fs = (const float*)d_in[2];
  const float* wq = (const float*)d_in[3];
  const float* wk = (const float*)d_in[4];
  const float* wv = (const float*)d_in[5];
  const float* wo = (const float*)d_in[6];
  float* out = (float*)d_out;
  char* ws = (char*)d_ws;

  unsigned short* xb    = (unsigned short*)(ws + 0);          // [4096][2048]
  unsigned short* wqkvb = (unsigned short*)(ws + 16777216);   // [3072][2048]
  unsigned short* wob   = (unsigned short*)(ws + 29360128);   // [2048][2048]
  unsigned short* Qb    = (unsigned short*)(ws + 62914560);   // [2][32][2048][64]
  unsigned short* Kb    = (unsigned short*)(ws + 79691776);   // [2][8][2048][64]
  unsigned short* Vtb   = (unsigned short*)(ws + 83886080);   // [2][8][64][2048]
  unsigned short* attnb = (unsigned short*)(ws + 88080384);   // [4096][2048]

  k_cvt_all<<<18432, 256, 0, stream>>>(x, wq, wk, wv, wo, xb, wqkvb, wob);

  dim3 g1(24, 32);   // N=3072/128, M=4096/128 — fused RoPE/Vt epilogue
  k_gemm_qkv<<<g1, 256, 0, stream>>>(xb, wqkvb, fc, fs, Qb, Kb, Vtb);

  k_attn<<<512, 256, 0, stream>>>(Qb, Kb, Vtb, attnb);

  dim3 g2(16, 32);   // N=2048/128, M=4096/128
  k_gemm_bt<0><<<g2, 256, 0, stream>>>(attnb, wob, out, NROWS, DIMSZ, DIMSZ);
}